// Round 1
// 509.612 us; speedup vs baseline: 1.1148x; 1.1148x over previous
//
#include <hip/hip_runtime.h>

// NNMF fused: B=8192, NIN=3072, NOUT=512, 5 iterations.
// R7: Phase A register-resident + fp8.
//  R6 rocprof: Phase A re-read full h from LDS every slot (8 waves x 32
//  ds_read_b128 = 256 KB/CU/slot ~3.1k cy + 1.1k cy bank conflicts of the
//  8.1k cy slot) -> LDS-BW bound (MfmaUtil 24%, HBM 11%, VALU 19%).
//  Fix: h held as fp8 MFMA A-frags in VGPRs (64 regs), loaded from LDS once
//  per iteration; W1 fp8 B-frags (32 regs, half the bytes). Phase A MFMA ->
//  16x16x32 fp8 (same rate as bf16). Barriers are LDS-only (asm lgkmcnt(0)
//  + s_barrier) so global prefetches ride across; x prefetch issued a full
//  slot early. Scales: h x2^8 (safe, h<=1), W1 x2^12 -> acc = 2^20 * denom.
//  fp32 h master, exact-it0 d0inv, fp8 Phase B unchanged.

#define NIN 3072
#define NOUT 512

using bf16x8 = __attribute__((ext_vector_type(8))) short;
using f32x4  = __attribute__((ext_vector_type(4))) float;

__device__ __forceinline__ unsigned short f2bf(float f) {
    unsigned int u = __builtin_bit_cast(unsigned int, f);
    return (unsigned short)((u + 0x7fffu + ((u >> 16) & 1u)) >> 16);  // RNE
}
__device__ __forceinline__ float bf2f(unsigned short s) {
    unsigned int u = ((unsigned int)s) << 16;
    return __builtin_bit_cast(float, u);
}

// LDS-only barrier: all cross-wave deps in the slot loop are LDS; global
// loads are consumed by the issuing wave (compiler inserts use-site vmcnt).
#define LDS_BARRIER() do {                                   \
    asm volatile("s_waitcnt lgkmcnt(0)" ::: "memory");       \
    __builtin_amdgcn_s_barrier();                            \
    asm volatile("" ::: "memory");                           \
} while (0)

// ---------------------------------------------------------------------------
// prep_w: W (fp32 [512][3072]) ->
//   W2 (fp8 e4m3, x4096, pair-packed for Phase B):
//     byte addr = ((kcg*16 + pr)*64 + l)*16 + h8*8 + j
//     element: n = (pr*2+h8)*16 + (l&15), k = kcg*32 + (l>>4)*8 + j
//   W1 (fp8 e4m3, x4096, Phase A B-frags):
//     W1[((ktg*16+nc)*64 + l)*8 + j] = fp8(W[nc*32+(l>>4)*8+j][ktg*16+(l&15)]*4096)
// ---------------------------------------------------------------------------
__global__ void prep_w(const float* __restrict__ W,
                       unsigned char* __restrict__ W1,
                       unsigned char* __restrict__ W2) {
    int t = blockIdx.x * 256 + threadIdx.x;   // 0 .. 294911
    if (t < 98304) {
        // W2 fp8 pair-packed
        int f = t >> 6, l = t & 63;
        int kcg = f >> 4, pr = f & 15;
        int kbase = kcg * 32 + ((l >> 4) << 3);
        unsigned int words[4];
        #pragma unroll
        for (int h8 = 0; h8 < 2; ++h8) {
            int n = (pr * 2 + h8) * 16 + (l & 15);
            const float* src = W + (size_t)n * NIN + kbase;
            float v[8];
            #pragma unroll
            for (int j = 0; j < 8; ++j) v[j] = src[j] * 4096.0f;
            int lo32 = __builtin_amdgcn_cvt_pk_fp8_f32(v[0], v[1], 0, false);
            lo32     = __builtin_amdgcn_cvt_pk_fp8_f32(v[2], v[3], lo32, true);
            int hi32 = __builtin_amdgcn_cvt_pk_fp8_f32(v[4], v[5], 0, false);
            hi32     = __builtin_amdgcn_cvt_pk_fp8_f32(v[6], v[7], hi32, true);
            words[h8 * 2]     = (unsigned int)lo32;
            words[h8 * 2 + 1] = (unsigned int)hi32;
        }
        *reinterpret_cast<uint4*>(W2 + (size_t)t * 16) =
            *reinterpret_cast<uint4*>(words);
    } else {
        // W1 fp8 B-frags for Phase A
        int u = t - 98304;                    // 0 .. 196607
        int f = u >> 6, l = u & 63;
        int ktg = f >> 4, nc = f & 15;
        int k = ktg * 16 + (l & 15);
        int nb = nc * 32 + ((l >> 4) << 3);
        float v[8];
        #pragma unroll
        for (int j = 0; j < 8; ++j) v[j] = W[(size_t)(nb + j) * NIN + k] * 4096.0f;
        int lo32 = __builtin_amdgcn_cvt_pk_fp8_f32(v[0], v[1], 0, false);
        lo32     = __builtin_amdgcn_cvt_pk_fp8_f32(v[2], v[3], lo32, true);
        int hi32 = __builtin_amdgcn_cvt_pk_fp8_f32(v[4], v[5], 0, false);
        hi32     = __builtin_amdgcn_cvt_pk_fp8_f32(v[6], v[7], hi32, true);
        uint2 o; o.x = (unsigned int)lo32; o.y = (unsigned int)hi32;
        *reinterpret_cast<uint2*>(W1 + (size_t)u * 8) = o;
    }
}

// ---------------------------------------------------------------------------
// prep_cs: d0inv[k] = 1 / (sum_n h_init[n]*W[n][k] + 1e-20)  (it0 denom, exact fp32)
// ---------------------------------------------------------------------------
__global__ void prep_cs(const float* __restrict__ W, const float* __restrict__ h_init,
                        float* __restrict__ d0inv) {
    int k = blockIdx.x * 256 + threadIdx.x;   // 0..3071
    float s = 0.f;
    for (int n = 0; n < NOUT; ++n) s += h_init[n] * W[(size_t)n * NIN + k];
    d0inv[k] = 1.0f / (s + 1e-20f);
}

// ---------------------------------------------------------------------------
// prep_x: per-row normalize x and store bf16 (coalesced, R3-verified).
// ---------------------------------------------------------------------------
__global__ void prep_x(const float* __restrict__ x, unsigned short* __restrict__ X2) {
    int b = blockIdx.x;
    int t = threadIdx.x;                      // 256 threads
    const float4* r4 = reinterpret_cast<const float4*>(x + (size_t)b * NIN);
    float s = 0.f;
    float4 v0 = r4[t], v1 = r4[t + 256], v2 = r4[t + 512];
    s = v0.x + v0.y + v0.z + v0.w + v1.x + v1.y + v1.z + v1.w + v2.x + v2.y + v2.z + v2.w;
    #pragma unroll
    for (int off = 32; off > 0; off >>= 1) s += __shfl_down(s, off, 64);
    __shared__ float wsum[4];
    int w = t >> 6, l = t & 63;
    if (l == 0) wsum[w] = s;
    __syncthreads();
    float inv = 1.0f / (wsum[0] + wsum[1] + wsum[2] + wsum[3] + 1e-20f);
    unsigned short* orow = X2 + (size_t)b * NIN;
    #pragma unroll
    for (int c = 0; c < 3; ++c) {
        float4 v = (c == 0) ? v0 : (c == 1) ? v1 : v2;
        ushort4 o;
        o.x = f2bf(v.x * inv); o.y = f2bf(v.y * inv);
        o.z = f2bf(v.z * inv); o.w = f2bf(v.w * inv);
        *reinterpret_cast<ushort4*>(orow + (t + c * 256) * 4) = o;
    }
}

// ---------------------------------------------------------------------------
// Main kernel. 256 blocks x 512 threads (8 waves), 32 rows/block, 1 block/CU
// (2 waves/SIMD). Phase A fp8 with register-resident h-frags; Phase B fp8.
// ---------------------------------------------------------------------------
__global__ __launch_bounds__(512, 2) void nnmf_main(
    const unsigned short* __restrict__ X2,
    const unsigned char* __restrict__ W1,
    const unsigned char* __restrict__ W2,
    const float* __restrict__ d0inv,
    const float* __restrict__ h_init,
    float* __restrict__ out)
{
    __shared__ unsigned char  h8_lds[32 * 528];  // 16.9 KB (fp8 h, x256)
    __shared__ unsigned short x_lds[32 * 136];   // 8.7 KB
    __shared__ unsigned char  r8_lds[32 * 144];  // 4.6 KB (fp8 r, stride 144B)
    __shared__ float red[8][32];

    const int tid = threadIdx.x;
    const int w  = tid >> 6;        // wave 0..7
    const int l  = tid & 63;
    const int lo = l & 15;
    const int hi = l >> 4;          // 0..3
    const int b0 = blockIdx.x * 32;

    // fp32 h master in registers, C-layout: row=m*16+hi*4+i, col=w*64+nt*16+lo
    float h_reg[2][4][4];
    #pragma unroll
    for (int nt = 0; nt < 4; ++nt) {
        float hv = h_init[w * 64 + nt * 16 + lo];
        #pragma unroll
        for (int m = 0; m < 2; ++m)
            #pragma unroll
            for (int i = 0; i < 4; ++i)
                h_reg[m][nt][i] = hv;
    }

    // x staging: thread -> (row, 16B chunk)
    const int xrow = tid >> 4, xcc = tid & 15;
    const uint4* xg = reinterpret_cast<const uint4*>(X2 + (size_t)(b0 + xrow) * NIN + xcc * 8);
    unsigned short* xdst = &x_lds[xrow * 136 + xcc * 8];

    // W base pointers (fp8)
    const unsigned char* w1base = W1 + ((size_t)(w * 16)) * 512 + (size_t)l * 8;   // +s*65536 B, +nc*512 B
    const unsigned char* w2base = W2 + (size_t)(w * 2) * 1024 + (size_t)l * 16;    // +s*65536 B +kc*16384 B +p*1024 B

    // prime pipeline: x[0] -> LDS, x[1] -> reg
    *reinterpret_cast<uint4*>(xdst) = xg[0];
    uint4 xnext = xg[16];
    long long w1buf[16];            // fp8 W1 B-frags (loaded from it0 s==23 on)
    long long hfr[2][16];           // fp8 h A-frags (loaded per iteration, it>=1)
    __syncthreads();

    const float DSCL = 9.5367431640625e-07f;  // 2^-20: undo h x256 * W1 x4096
    const float TS   = 1.0f / 65536.0f;       // undo W2 x4096 and r x16 scales
    f32x4 tacc[2][4];

    for (int it = 0; it < 5; ++it) {
        // h A-frags: LDS -> regs ONCE per iteration (was: every slot)
        if (it != 0) {
            #pragma unroll
            for (int m = 0; m < 2; ++m)
                #pragma unroll
                for (int nc = 0; nc < 16; ++nc)
                    hfr[m][nc] = *reinterpret_cast<const long long*>(
                        &h8_lds[(m * 16 + lo) * 528 + nc * 32 + hi * 8]);
        }

        #pragma unroll
        for (int m = 0; m < 2; ++m)
            #pragma unroll
            for (int nt = 0; nt < 4; ++nt)
                tacc[m][nt] = (f32x4){0.f, 0.f, 0.f, 0.f};

        for (int s = 0; s < 24; ++s) {
            const int sn  = (s + 1 == 24) ? 0 : s + 1;
            const int sn2 = (s + 2 >= 24) ? (s + 2 - 24) : s + 2;

            // ---- issue x[s+2] prefetch a full slot early (drained by next slot)
            uint4 xfut = xg[sn2 * 16];

            // ---- issue W2[s] fp8 loads (8 x dwordx4 = 16 frags; consumed in Phase B)
            uint4 w2v[8];
            {
                const unsigned char* w2p = w2base + (size_t)s * 65536;
                #pragma unroll
                for (int kc = 0; kc < 4; ++kc)
                    #pragma unroll
                    for (int p = 0; p < 2; ++p)
                        w2v[kc * 2 + p] = *reinterpret_cast<const uint4*>(
                            w2p + (size_t)kc * 16384 + p * 1024);
            }

            f32x4 d0, d1;
            float dv = 0.f;
            if (it == 0) {
                dv = d0inv[s * 128 + w * 16 + lo];   // exact it0 denom reciprocal
            } else {
                // ---- Phase A (fp8): denom tiles, h and W1 operands register-resident
                f32x4 a0a = {0,0,0,0}, a0b = {0,0,0,0}, a1a = {0,0,0,0}, a1b = {0,0,0,0};
                #pragma unroll
                for (int nc = 0; nc < 16; nc += 2) {
                    a0a = __builtin_amdgcn_mfma_f32_16x16x32_fp8_fp8(hfr[0][nc],     w1buf[nc],     a0a, 0, 0, 0);
                    a1a = __builtin_amdgcn_mfma_f32_16x16x32_fp8_fp8(hfr[1][nc],     w1buf[nc],     a1a, 0, 0, 0);
                    a0b = __builtin_amdgcn_mfma_f32_16x16x32_fp8_fp8(hfr[0][nc + 1], w1buf[nc + 1], a0b, 0, 0, 0);
                    a1b = __builtin_amdgcn_mfma_f32_16x16x32_fp8_fp8(hfr[1][nc + 1], w1buf[nc + 1], a1b, 0, 0, 0);
                }
                d0 = a0a + a0b;
                d1 = a1a + a1b;
            }

            // ---- r = 16 * x * rcp(denom + eps) -> fp8 in r8_lds
            #pragma unroll
            for (int i = 0; i < 4; ++i) {
                int row0 = hi * 4 + i;
                float x0 = bf2f(x_lds[row0 * 136 + w * 16 + lo]) * 16.0f;
                float x1 = bf2f(x_lds[(16 + row0) * 136 + w * 16 + lo]) * 16.0f;
                float r0, r1;
                if (it == 0) { r0 = x0 * dv; r1 = x1 * dv; }
                else {
                    r0 = x0 * __builtin_amdgcn_rcpf(fmaf(d0[i], DSCL, 1e-20f));
                    r1 = x1 * __builtin_amdgcn_rcpf(fmaf(d1[i], DSCL, 1e-20f));
                }
                int c0 = __builtin_amdgcn_cvt_pk_fp8_f32(r0, r0, 0, false);
                int c1 = __builtin_amdgcn_cvt_pk_fp8_f32(r1, r1, 0, false);
                r8_lds[row0 * 144 + w * 16 + lo] = (unsigned char)(c0 & 0xff);
                r8_lds[(16 + row0) * 144 + w * 16 + lo] = (unsigned char)(c1 & 0xff);
            }
            LDS_BARRIER();   // barrier A (LDS-only: global prefetches stay in flight)

            // ---- Phase B 1st half (kc 0,1), fp8 MFMA
            #pragma unroll
            for (int kc = 0; kc < 2; ++kc) {
                long long ra0 = *reinterpret_cast<const long long*>(&r8_lds[lo * 144 + kc * 32 + hi * 8]);
                long long ra1 = *reinterpret_cast<const long long*>(&r8_lds[(16 + lo) * 144 + kc * 32 + hi * 8]);
                #pragma unroll
                for (int p = 0; p < 2; ++p) {
                    union { uint4 v; long long q[2]; } u;
                    u.v = w2v[kc * 2 + p];
                    #pragma unroll
                    for (int h8 = 0; h8 < 2; ++h8) {
                        int nt = p * 2 + h8;
                        tacc[0][nt] = __builtin_amdgcn_mfma_f32_16x16x32_fp8_fp8(ra0, u.q[h8], tacc[0][nt], 0, 0, 0);
                        tacc[1][nt] = __builtin_amdgcn_mfma_f32_16x16x32_fp8_fp8(ra1, u.q[h8], tacc[1][nt], 0, 0, 0);
                    }
                }
            }

            // ---- reload w1buf with W1[sn] fp8 (skip during it0 except last slot)
            if (it > 0 || s == 23) {
                const unsigned char* w1p = w1base + (size_t)sn * 65536;
                #pragma unroll
                for (int nc = 0; nc < 16; ++nc)
                    w1buf[nc] = *reinterpret_cast<const long long*>(w1p + (size_t)nc * 512);
            }

            // ---- Phase B 2nd half (kc 2,3)
            #pragma unroll
            for (int kc = 2; kc < 4; ++kc) {
                long long ra0 = *reinterpret_cast<const long long*>(&r8_lds[lo * 144 + kc * 32 + hi * 8]);
                long long ra1 = *reinterpret_cast<const long long*>(&r8_lds[(16 + lo) * 144 + kc * 32 + hi * 8]);
                #pragma unroll
                for (int p = 0; p < 2; ++p) {
                    union { uint4 v; long long q[2]; } u;
                    u.v = w2v[kc * 2 + p];
                    #pragma unroll
                    for (int h8 = 0; h8 < 2; ++h8) {
                        int nt = p * 2 + h8;
                        tacc[0][nt] = __builtin_amdgcn_mfma_f32_16x16x32_fp8_fp8(ra0, u.q[h8], tacc[0][nt], 0, 0, 0);
                        tacc[1][nt] = __builtin_amdgcn_mfma_f32_16x16x32_fp8_fp8(ra1, u.q[h8], tacc[1][nt], 0, 0, 0);
                    }
                }
            }

            // ---- stage x[s+1] (loaded a slot+ ago), rotate prefetch regs
            *reinterpret_cast<uint4*>(xdst) = xnext;
            xnext = xfut;
            LDS_BARRIER();   // barrier B
        }

        // ---- boundary: h_new = normalize(h * (1 + t*2^-16)), fp32 in regs
        float p[2][4];
        #pragma unroll
        for (int m = 0; m < 2; ++m)
            #pragma unroll
            for (int i = 0; i < 4; ++i) p[m][i] = 0.f;

        #pragma unroll
        for (int m = 0; m < 2; ++m)
            #pragma unroll
            for (int nt = 0; nt < 4; ++nt)
                #pragma unroll
                for (int i = 0; i < 4; ++i) {
                    float v = h_reg[m][nt][i] * (1.f + tacc[m][nt][i] * TS);  // EPSILON_0 = 1
                    h_reg[m][nt][i] = v;
                    p[m][i] += v;
                }
        #pragma unroll
        for (int mask = 1; mask < 16; mask <<= 1)
            #pragma unroll
            for (int m = 0; m < 2; ++m)
                #pragma unroll
                for (int i = 0; i < 4; ++i)
                    p[m][i] += __shfl_xor(p[m][i], mask, 64);
        if (lo == 0) {
            #pragma unroll
            for (int m = 0; m < 2; ++m)
                #pragma unroll
                for (int i = 0; i < 4; ++i)
                    red[w][m * 16 + hi * 4 + i] = p[m][i];
        }
        __syncthreads();
        float inv[2][4];
        #pragma unroll
        for (int m = 0; m < 2; ++m)
            #pragma unroll
            for (int i = 0; i < 4; ++i) {
                int row = m * 16 + hi * 4 + i;
                float S = 0.f;
                #pragma unroll
                for (int ww = 0; ww < 8; ++ww) S += red[ww][row];
                inv[m][i] = 1.f / (S + 1e-20f);
            }

        if (it < 4) {
            #pragma unroll
            for (int m = 0; m < 2; ++m)
                #pragma unroll
                for (int nt = 0; nt < 4; ++nt)
                    #pragma unroll
                    for (int i = 0; i < 4; ++i) {
                        int row = m * 16 + hi * 4 + i;
                        int col = w * 64 + nt * 16 + lo;
                        float hv = h_reg[m][nt][i] * inv[m][i];
                        h_reg[m][nt][i] = hv;
                        int c = __builtin_amdgcn_cvt_pk_fp8_f32(hv * 256.0f, hv * 256.0f, 0, false);
                        h8_lds[row * 528 + col] = (unsigned char)(c & 0xff);
                    }
            __syncthreads();
        } else {
            #pragma unroll
            for (int m = 0; m < 2; ++m)
                #pragma unroll
                for (int nt = 0; nt < 4; ++nt)
                    #pragma unroll
                    for (int i = 0; i < 4; ++i) {
                        int row = m * 16 + hi * 4 + i;
                        int col = w * 64 + nt * 16 + lo;
                        out[(size_t)(b0 + row) * 512 + col] = h_reg[m][nt][i] * inv[m][i];
                    }
        }
    }
}

extern "C" void kernel_launch(void* const* d_in, const int* in_sizes, int n_in,
                              void* d_out, int out_size, void* d_ws, size_t ws_size,
                              hipStream_t stream) {
    const float* x   = (const float*)d_in[0];   // [8192][3072]
    const float* wgt = (const float*)d_in[1];   // [512][3072]
    const float* h0  = (const float*)d_in[2];   // [512]
    float* out = (float*)d_out;

    // ws: X2 bf16 50,331,648 | W1 fp8 1,572,864 | W2 fp8 1,572,864 | d0inv 12,288
    unsigned short* X2 = (unsigned short*)d_ws;
    unsigned char*  W1 = (unsigned char*)((char*)d_ws + 50331648);
    unsigned char*  W2 = (unsigned char*)((char*)d_ws + 51904512);
    float* d0inv       = (float*)((char*)d_ws + 53477376);

    prep_w<<<1152, 256, 0, stream>>>(wgt, W1, W2);
    prep_cs<<<12, 256, 0, stream>>>(wgt, h0, d0inv);
    prep_x<<<8192, 256, 0, stream>>>(x, X2);
    nnmf_main<<<256, 512, 0, stream>>>(X2, W1, W2, d0inv, h0, out);
}